// Round 1
// baseline (214.221 us; speedup 1.0000x reference)
//
#include <hip/hip_runtime.h>

#define D      1024
#define SEQ    128
#define BATCH  256
#define DQ     256
#define TEXTC  768

// ---------------------------------------------------------------------------
// Kernel 0: build act[256][1024] = [ relu(sv@W1+b1) (256) | captions (768) ]
//           and init comb[256][1024] = style_b2[d] + text_b[d]
// One thread per element of the 256x1024 index space (reused for both jobs).
// ---------------------------------------------------------------------------
__global__ __launch_bounds__(256) void prep_kernel(
    const float* __restrict__ style_vectors,  // [256][5]
    const float* __restrict__ page_captions,  // [256][768]
    const float* __restrict__ style_w1,       // [5][256]
    const float* __restrict__ style_b1,       // [256]
    const float* __restrict__ style_b2,       // [1024]
    const float* __restrict__ text_b,         // [1024]
    float* __restrict__ act,                  // [256][1024]
    float* __restrict__ comb)                 // [256][1024]
{
    int i = blockIdx.x * 256 + threadIdx.x;   // 0 .. 262143
    int b = i >> 10;
    int k = i & 1023;
    float a;
    if (k < DQ) {
        float h = style_b1[k];
#pragma unroll
        for (int j = 0; j < 5; ++j)
            h = fmaf(style_vectors[b * 5 + j], style_w1[j * DQ + k], h);
        a = fmaxf(h, 0.0f);
    } else {
        a = page_captions[b * TEXTC + (k - DQ)];
    }
    act[i]  = a;
    comb[i] = style_b2[k] + text_b[k];
}

// ---------------------------------------------------------------------------
// Kernel 1: comb[m][n] += sum_k act[m][k] * W[k][n]
// W is the virtual concat [style_w2 (256 rows); text_w (768 rows)].
// Block tile 64x64, 256 threads, 4x4 micro-tile. K split x4 (z-dim) with
// fp32 atomicAdd so all 256 blocks / 256 CUs are busy.
// ---------------------------------------------------------------------------
__global__ __launch_bounds__(256) void gemm_kernel(
    const float* __restrict__ act,       // [256][1024]
    const float* __restrict__ style_w2,  // [256][1024]
    const float* __restrict__ text_w,    // [768][1024]
    float* __restrict__ comb)            // [256][1024] accumulate
{
    __shared__ float As[16][64];   // [k][m]
    __shared__ float Bs[16][64];   // [k][n]

    const int m0  = blockIdx.x * 64;
    const int n0  = blockIdx.y * 64;
    const int k0  = blockIdx.z * 256;
    const int tid = threadIdx.x;
    const int tm  = tid >> 4;     // 0..15
    const int tn  = tid & 15;     // 0..15

    float acc[4][4] = {};

    for (int kc = 0; kc < 256; kc += 16) {
        // Stage A tile: 64 m x 16 k (one float4 per thread, coalesced along k)
        {
            int m  = tid >> 2;                  // 0..63
            int kq = tid & 3;                   // float4 slot in 16 k
            float4 av = *(const float4*)&act[(m0 + m) * D + k0 + kc + kq * 4];
            As[kq * 4 + 0][m] = av.x;
            As[kq * 4 + 1][m] = av.y;
            As[kq * 4 + 2][m] = av.z;
            As[kq * 4 + 3][m] = av.w;
        }
        // Stage B tile: 16 k x 64 n (one float4 per thread, coalesced along n)
        {
            int kk   = tid >> 4;                // 0..15
            int nq   = tid & 15;                // 0..15
            int krow = k0 + kc + kk;
            const float* Wrow = (krow < DQ) ? &style_w2[krow * D]
                                            : &text_w[(krow - DQ) * D];
            *(float4*)&Bs[kk][nq * 4] = *(const float4*)&Wrow[n0 + nq * 4];
        }
        __syncthreads();

#pragma unroll
        for (int kk = 0; kk < 16; ++kk) {
            float4 a4 = *(const float4*)&As[kk][tm * 4];
            float4 b4 = *(const float4*)&Bs[kk][tn * 4];
            float av[4] = {a4.x, a4.y, a4.z, a4.w};
            float bv[4] = {b4.x, b4.y, b4.z, b4.w};
#pragma unroll
            for (int ii = 0; ii < 4; ++ii)
#pragma unroll
                for (int jj = 0; jj < 4; ++jj)
                    acc[ii][jj] = fmaf(av[ii], bv[jj], acc[ii][jj]);
        }
        __syncthreads();
    }

#pragma unroll
    for (int ii = 0; ii < 4; ++ii) {
        int m = m0 + tm * 4 + ii;
#pragma unroll
        for (int jj = 0; jj < 4; ++jj)
            atomicAdd(&comb[m * D + n0 + tn * 4 + jj], acc[ii][jj]);
    }
}

// ---------------------------------------------------------------------------
// Kernel 2: out[b,s,:] = type_emb[et] + pos_emb[ei] + final_pos_emb[s]
//                        + (et==1 ? comb[b] : 0)
//           mask[b,s]  = (et==0) ? 1 : 0
// One block per (b,s) row; 256 lanes x float4 = 4 KB coalesced write.
// ---------------------------------------------------------------------------
__global__ __launch_bounds__(256) void scatter_kernel(
    const int* __restrict__ types,          // [256][128]
    const int* __restrict__ indices,        // [256][128]
    const float* __restrict__ type_emb,     // [5][1024]
    const float* __restrict__ pos_emb,      // [128][1024]
    const float* __restrict__ final_pos_emb,// [128][1024]
    const float* __restrict__ comb,         // [256][1024]
    float* __restrict__ out_emb,            // [256][128][1024]
    float* __restrict__ out_mask)           // [256][128]
{
    const int bs = blockIdx.x;        // 0..32767
    const int b  = bs >> 7;
    const int s  = bs & 127;
    const int et = types[bs];
    const int ei = indices[bs];
    const int tid = threadIdx.x;

    const float4* te = (const float4*)&type_emb[et * D];
    const float4* pe = (const float4*)&pos_emb[ei * D];
    const float4* fe = (const float4*)&final_pos_emb[s * D];

    float4 t = te[tid];
    float4 p = pe[tid];
    float4 f = fe[tid];
    float4 v;
    v.x = t.x + p.x + f.x;
    v.y = t.y + p.y + f.y;
    v.z = t.z + p.z + f.z;
    v.w = t.w + p.w + f.w;
    if (et == 1) {
        float4 c = ((const float4*)&comb[b * D])[tid];
        v.x += c.x; v.y += c.y; v.z += c.z; v.w += c.w;
    }
    ((float4*)out_emb)[bs * 256 + tid] = v;

    if (tid == 0)
        out_mask[bs] = (et == 0) ? 1.0f : 0.0f;
}

// ---------------------------------------------------------------------------
extern "C" void kernel_launch(void* const* d_in, const int* in_sizes, int n_in,
                              void* d_out, int out_size, void* d_ws, size_t ws_size,
                              hipStream_t stream) {
    const int*   element_types   = (const int*)  d_in[0];
    const int*   element_indices = (const int*)  d_in[1];
    const float* style_vectors   = (const float*)d_in[2];
    const float* page_captions   = (const float*)d_in[3];
    const float* type_emb        = (const float*)d_in[4];
    const float* pos_emb         = (const float*)d_in[5];
    const float* style_w1        = (const float*)d_in[6];
    const float* style_b1        = (const float*)d_in[7];
    const float* style_w2        = (const float*)d_in[8];
    const float* style_b2        = (const float*)d_in[9];
    const float* text_w          = (const float*)d_in[10];
    const float* text_b          = (const float*)d_in[11];
    const float* final_pos_emb   = (const float*)d_in[12];

    float* act  = (float*)d_ws;                       // 256*1024 f32 = 1 MB
    float* comb = (float*)d_ws + BATCH * D;           // 256*1024 f32 = 1 MB

    float* out_emb  = (float*)d_out;                          // 256*128*1024
    float* out_mask = (float*)d_out + BATCH * SEQ * D;        // 256*128

    // 1) activations + comb init (ws is re-poisoned every call)
    prep_kernel<<<(BATCH * D) / 256, 256, 0, stream>>>(
        style_vectors, page_captions, style_w1, style_b1, style_b2, text_b,
        act, comb);

    // 2) combined = act @ [style_w2; text_w]  (K split x4, atomic accumulate)
    gemm_kernel<<<dim3(BATCH / 64, D / 64, 4), 256, 0, stream>>>(
        act, style_w2, text_w, comb);

    // 3) big masked gather-add write
    scatter_kernel<<<BATCH * SEQ, 256, 0, stream>>>(
        element_types, element_indices, type_emb, pos_emb, final_pos_emb,
        comb, out_emb, out_mask);
}

// Round 2
// 206.918 us; speedup vs baseline: 1.0353x; 1.0353x over previous
//
#include <hip/hip_runtime.h>

#define D      1024
#define SEQ    128
#define BATCH  256
#define DQ     256
#define TEXTC  768

typedef float f32x4 __attribute__((ext_vector_type(4)));

// ---------------------------------------------------------------------------
// Kernel 1: split-K partial GEMM with fused activation build.
//   part[z][m][n] = sum_{k in chunk z} act[m][k] * W[k][n]   (+biases for z=0)
// where act[m][k<256] = relu(sv@W1+b1) computed in-register (chunk z=0),
//       act[m][k>=256] = page_captions[m][k-256]             (chunks z=1..3),
// and W = [style_w2 (rows 0..255); text_w (rows 256..1023)].
// Grid (4,16,4) = 256 blocks, 256 threads, 64x64 tile, 4x4 micro-tile.
// No atomics: each z writes its own disjoint partial buffer.
// ---------------------------------------------------------------------------
__global__ __launch_bounds__(256) void gemm_fused(
    const float* __restrict__ style_vectors,  // [256][5]
    const float* __restrict__ page_captions,  // [256][768]
    const float* __restrict__ style_w1,       // [5][256]
    const float* __restrict__ style_b1,       // [256]
    const float* __restrict__ style_w2,       // [256][1024]
    const float* __restrict__ style_b2,       // [1024]
    const float* __restrict__ text_w,         // [768][1024]
    const float* __restrict__ text_b,         // [1024]
    float* __restrict__ part)                 // [4][256][1024]
{
    // pad rows to 68 floats: keeps float4 alignment (68*4 B = 272 = 16*17)
    // and makes the A transpose-write 2-way (free) instead of 4-way.
    __shared__ float As[16][68];   // [k][m]
    __shared__ float Bs[16][68];   // [k][n]

    const int m0  = blockIdx.x * 64;
    const int n0  = blockIdx.y * 64;
    const int z   = blockIdx.z;            // K chunk: k in [z*256, z*256+256)
    const int tid = threadIdx.x;
    const int tm  = tid >> 4;              // 0..15 (micro-tile row group)
    const int tn  = tid & 15;              // 0..15 (micro-tile col group)

    // A staging coords: thread covers (m0+am, kc+ak .. kc+ak+3)
    const int am = tid >> 2;               // 0..63
    const int ak = (tid & 3) * 4;          // 0,4,8,12

    float sv[5];
    if (z == 0) {
#pragma unroll
        for (int j = 0; j < 5; ++j) sv[j] = style_vectors[(m0 + am) * 5 + j];
    }

    float acc[4][4] = {};

    for (int kc = 0; kc < 256; kc += 16) {
        // ---- stage A tile: 64 m x 16 k ----
        if (z == 0) {
            int k = kc + ak;               // global k (style region, k < 256)
#pragma unroll
            for (int r = 0; r < 4; ++r) {
                float h = style_b1[k + r];
#pragma unroll
                for (int j = 0; j < 5; ++j)
                    h = fmaf(sv[j], style_w1[j * DQ + k + r], h);
                As[ak + r][am] = fmaxf(h, 0.0f);
            }
        } else {
            float4 av = *(const float4*)
                &page_captions[(m0 + am) * TEXTC + (z * 256 - DQ) + kc + ak];
            As[ak + 0][am] = av.x;
            As[ak + 1][am] = av.y;
            As[ak + 2][am] = av.z;
            As[ak + 3][am] = av.w;
        }
        // ---- stage B tile: 16 k x 64 n ----
        {
            int kk   = tid >> 4;           // 0..15
            int nq   = (tid & 15) * 4;     // 0..60
            int krow = z * 256 + kc + kk;
            const float* Wrow = (z == 0) ? &style_w2[krow * D]
                                         : &text_w[(krow - DQ) * D];
            *(float4*)&Bs[kk][nq] = *(const float4*)&Wrow[n0 + nq];
        }
        __syncthreads();

#pragma unroll
        for (int kk = 0; kk < 16; ++kk) {
            f32x4 a4 = *(const f32x4*)&As[kk][tm * 4];
            f32x4 b4 = *(const f32x4*)&Bs[kk][tn * 4];
#pragma unroll
            for (int ii = 0; ii < 4; ++ii)
#pragma unroll
                for (int jj = 0; jj < 4; ++jj)
                    acc[ii][jj] = fmaf(a4[ii], b4[jj], acc[ii][jj]);
        }
        __syncthreads();
    }

    // epilogue: plain stores to this chunk's private partial buffer
    float* dst = part + (size_t)z * BATCH * D;
    const int n = n0 + tn * 4;
#pragma unroll
    for (int ii = 0; ii < 4; ++ii) {
        int m = m0 + tm * 4 + ii;
        f32x4 v = {acc[ii][0], acc[ii][1], acc[ii][2], acc[ii][3]};
        if (z == 0) {
            v[0] += style_b2[n + 0] + text_b[n + 0];
            v[1] += style_b2[n + 1] + text_b[n + 1];
            v[2] += style_b2[n + 2] + text_b[n + 2];
            v[3] += style_b2[n + 3] + text_b[n + 3];
        }
        *(f32x4*)&dst[m * D + n] = v;
    }
}

// ---------------------------------------------------------------------------
// Kernel 2: comb = part[0] + part[1] + part[2] + part[3]   (float4-wide)
// 65536 float4s, 256 blocks x 256 threads. ~2 us.
// ---------------------------------------------------------------------------
__global__ __launch_bounds__(256) void reduce_part(
    const float* __restrict__ part,   // [4][256][1024]
    float* __restrict__ comb)         // [256][1024]
{
    const int i = blockIdx.x * 256 + threadIdx.x;      // float4 index
    const f32x4* p = (const f32x4*)part;
    const int Q = BATCH * D / 4;                        // 65536
    f32x4 v = p[i] + p[i + Q] + p[i + 2 * Q] + p[i + 3 * Q];
    ((f32x4*)comb)[i] = v;
}

// ---------------------------------------------------------------------------
// Kernel 3: out[b,s,:] = type_emb[et] + pos_emb[ei] + final_pos_emb[s]
//                        + (et==1 ? comb[b] : 0)
//           mask[b,s]  = (et==0) ? 1 : 0
// One block per (b,s) row; 256 lanes x float4; nontemporal output stores.
// ---------------------------------------------------------------------------
__global__ __launch_bounds__(256) void scatter_kernel(
    const int* __restrict__ types,           // [256][128]
    const int* __restrict__ indices,         // [256][128]
    const float* __restrict__ type_emb,      // [5][1024]
    const float* __restrict__ pos_emb,       // [128][1024]
    const float* __restrict__ final_pos_emb, // [128][1024]
    const float* __restrict__ comb,          // [256][1024]
    float* __restrict__ out_emb,             // [256][128][1024]
    float* __restrict__ out_mask)            // [256][128]
{
    const int bs = blockIdx.x;        // 0..32767
    const int b  = bs >> 7;
    const int s  = bs & 127;
    const int et = types[bs];
    const int ei = indices[bs];
    const int tid = threadIdx.x;

    f32x4 t = ((const f32x4*)&type_emb[et * D])[tid];
    f32x4 p = ((const f32x4*)&pos_emb[ei * D])[tid];
    f32x4 f = ((const f32x4*)&final_pos_emb[s * D])[tid];
    f32x4 v = t + p + f;
    if (et == 1)
        v = v + ((const f32x4*)&comb[b * D])[tid];

    __builtin_nontemporal_store(v, &((f32x4*)out_emb)[bs * 256 + tid]);

    if (tid == 0)
        out_mask[bs] = (et == 0) ? 1.0f : 0.0f;
}

// ---------------------------------------------------------------------------
extern "C" void kernel_launch(void* const* d_in, const int* in_sizes, int n_in,
                              void* d_out, int out_size, void* d_ws, size_t ws_size,
                              hipStream_t stream) {
    const int*   element_types   = (const int*)  d_in[0];
    const int*   element_indices = (const int*)  d_in[1];
    const float* style_vectors   = (const float*)d_in[2];
    const float* page_captions   = (const float*)d_in[3];
    const float* type_emb        = (const float*)d_in[4];
    const float* pos_emb         = (const float*)d_in[5];
    const float* style_w1        = (const float*)d_in[6];
    const float* style_b1        = (const float*)d_in[7];
    const float* style_w2        = (const float*)d_in[8];
    const float* style_b2        = (const float*)d_in[9];
    const float* text_w          = (const float*)d_in[10];
    const float* text_b          = (const float*)d_in[11];
    const float* final_pos_emb   = (const float*)d_in[12];

    float* part = (float*)d_ws;                           // 4*256*1024 = 4 MB
    float* comb = (float*)d_ws + 4 * BATCH * D;           // 256*1024   = 1 MB

    float* out_emb  = (float*)d_out;                      // 256*128*1024
    float* out_mask = (float*)d_out + BATCH * SEQ * D;    // 256*128

    // 1) split-K GEMM (activation build fused into A staging; no atomics)
    gemm_fused<<<dim3(BATCH / 64, D / 64, 4), 256, 0, stream>>>(
        style_vectors, page_captions, style_w1, style_b1,
        style_w2, style_b2, text_w, text_b, part);

    // 2) combine partials
    reduce_part<<<BATCH * D / 4 / 256, 256, 0, stream>>>(part, comb);

    // 3) big masked gather-add write
    scatter_kernel<<<BATCH * SEQ, 256, 0, stream>>>(
        element_types, element_indices, type_emb, pos_emb, final_pos_emb,
        comb, out_emb, out_mask);
}

// Round 3
// 199.693 us; speedup vs baseline: 1.0728x; 1.0362x over previous
//
#include <hip/hip_runtime.h>

#define D      1024
#define SEQ    128
#define BATCH  256
#define DQ     256
#define TEXTC  768

typedef float f32x4 __attribute__((ext_vector_type(4)));
typedef float f32x2 __attribute__((ext_vector_type(2)));

// ---------------------------------------------------------------------------
// Kernel 1: split-K partial GEMM, fused activation build.
//   part[z][m][n] = sum_{k in [z*256,z*256+256)} act[m][k] * W[k][n]  (+bias z=0)
// act[m][k<256]  = relu(sv@W1+b1) computed in-register during A staging (z=0)
// act[m][k>=256] = page_captions[m][k-256]                            (z=1..3)
// W = [style_w2 rows 0..255 ; text_w rows 256..1023].
// Grid (8,16,4) = 512 blocks (2/CU, 8 waves/CU), 32x64 tile, 2x4 micro-tile.
// ---------------------------------------------------------------------------
__global__ __launch_bounds__(256) void gemm_fused(
    const float* __restrict__ style_vectors,  // [256][5]
    const float* __restrict__ page_captions,  // [256][768]
    const float* __restrict__ style_w1,       // [5][256]
    const float* __restrict__ style_b1,       // [256]
    const float* __restrict__ style_w2,       // [256][1024]
    const float* __restrict__ style_b2,       // [1024]
    const float* __restrict__ text_w,         // [768][1024]
    const float* __restrict__ text_b,         // [1024]
    float* __restrict__ part)                 // [4][256][1024]
{
    __shared__ float As[16][36];   // [k][m], +pad
    __shared__ float Bs[16][68];   // [k][n], +pad (16B-aligned rows)

    const int m0  = blockIdx.x * 32;
    const int n0  = blockIdx.y * 64;
    const int z   = blockIdx.z;            // K chunk: [z*256, z*256+256)
    const int tid = threadIdx.x;
    const int tm  = tid >> 4;              // 0..15 -> rows m0+tm*2 .. +1
    const int tn  = tid & 15;              // 0..15 -> cols n0+tn*4 .. +3

    // A staging (threads 0..127): thread covers (m0+am, kc+ak..kc+ak+3)
    const int am = tid >> 2;               // 0..31 (for tid<128)
    const int ak = (tid & 3) * 4;          // 0,4,8,12

    float sv[5];
    if (z == 0 && tid < 128) {
#pragma unroll
        for (int j = 0; j < 5; ++j) sv[j] = style_vectors[(m0 + am) * 5 + j];
    }

    float acc[2][4] = {};

    for (int kc = 0; kc < 256; kc += 16) {
        if (tid < 128) {
            if (z == 0) {
                int k = kc + ak;           // style region, k < 256
#pragma unroll
                for (int r = 0; r < 4; ++r) {
                    float h = style_b1[k + r];
#pragma unroll
                    for (int j = 0; j < 5; ++j)
                        h = fmaf(sv[j], style_w1[j * DQ + k + r], h);
                    As[ak + r][am] = fmaxf(h, 0.0f);
                }
            } else {
                float4 av = *(const float4*)
                    &page_captions[(m0 + am) * TEXTC + (z * 256 - DQ) + kc + ak];
                As[ak + 0][am] = av.x;
                As[ak + 1][am] = av.y;
                As[ak + 2][am] = av.z;
                As[ak + 3][am] = av.w;
            }
        }
        {
            int kk   = tid >> 4;           // 0..15
            int nq   = (tid & 15) * 4;     // 0..60
            int krow = z * 256 + kc + kk;
            const float* Wrow = (z == 0) ? &style_w2[krow * D]
                                         : &text_w[(krow - DQ) * D];
            *(float4*)&Bs[kk][nq] = *(const float4*)&Wrow[n0 + nq];
        }
        __syncthreads();

#pragma unroll
        for (int kk = 0; kk < 16; ++kk) {
            f32x2 a2 = *(const f32x2*)&As[kk][tm * 2];
            f32x4 b4 = *(const f32x4*)&Bs[kk][tn * 4];
#pragma unroll
            for (int ii = 0; ii < 2; ++ii)
#pragma unroll
                for (int jj = 0; jj < 4; ++jj)
                    acc[ii][jj] = fmaf(a2[ii], b4[jj], acc[ii][jj]);
        }
        __syncthreads();
    }

    float* dst = part + (size_t)z * BATCH * D;
    const int n = n0 + tn * 4;
#pragma unroll
    for (int ii = 0; ii < 2; ++ii) {
        int m = m0 + tm * 2 + ii;
        f32x4 v = {acc[ii][0], acc[ii][1], acc[ii][2], acc[ii][3]};
        if (z == 0) {
            v[0] += style_b2[n + 0] + text_b[n + 0];
            v[1] += style_b2[n + 1] + text_b[n + 1];
            v[2] += style_b2[n + 2] + text_b[n + 2];
            v[3] += style_b2[n + 3] + text_b[n + 3];
        }
        *(f32x4*)&dst[m * D + n] = v;
    }
}

// ---------------------------------------------------------------------------
// Kernel 2: comb = sum of 4 partials (float4-wide, nontemporal partial loads)
// ---------------------------------------------------------------------------
__global__ __launch_bounds__(256) void reduce_part(
    const float* __restrict__ part,   // [4][256][1024]
    float* __restrict__ comb)         // [256][1024]
{
    const int i = blockIdx.x * 256 + threadIdx.x;      // float4 index
    const f32x4* p = (const f32x4*)part;
    const int Q = BATCH * D / 4;                        // 65536
    f32x4 v = __builtin_nontemporal_load(&p[i])
            + __builtin_nontemporal_load(&p[i + Q])
            + __builtin_nontemporal_load(&p[i + 2 * Q])
            + __builtin_nontemporal_load(&p[i + 3 * Q]);
    ((f32x4*)comb)[i] = v;
}

// ---------------------------------------------------------------------------
// Kernel 3: out[b,s,:] = type_emb[et] + pos_emb[ei] + final_pos_emb[s]
//                        + (et==1 ? comb[b] : 0);  mask = (et==0)
// 4 rows per block, one 64-lane wave per row, 4 independent float4
// nontemporal stores per thread (deep store pipeline, no divergence:
// the et==1 branch is wave-uniform).
// ---------------------------------------------------------------------------
__global__ __launch_bounds__(256) void scatter_kernel(
    const int* __restrict__ types,           // [256][128]
    const int* __restrict__ indices,         // [256][128]
    const float* __restrict__ type_emb,      // [5][1024]
    const float* __restrict__ pos_emb,       // [128][1024]
    const float* __restrict__ final_pos_emb, // [128][1024]
    const float* __restrict__ comb,          // [256][1024]
    float* __restrict__ out_emb,             // [256][128][1024]
    float* __restrict__ out_mask)            // [256][128]
{
    const int tid  = threadIdx.x;
    const int wave = tid >> 6;
    const int lane = tid & 63;
    const int bs   = blockIdx.x * 4 + wave;   // 0..32767
    const int b    = bs >> 7;
    const int s    = bs & 127;
    const int et   = types[bs];
    const int ei   = indices[bs];

    const f32x4* te = (const f32x4*)&type_emb[et * D];
    const f32x4* pe = (const f32x4*)&pos_emb[ei * D];
    const f32x4* fe = (const f32x4*)&final_pos_emb[s * D];
    f32x4* dst = (f32x4*)out_emb + (size_t)bs * 256;

    if (et == 1) {
        const f32x4* cb = (const f32x4*)&comb[b * D];
#pragma unroll
        for (int j = 0; j < 4; ++j) {
            int idx = lane + 64 * j;
            f32x4 v = te[idx] + pe[idx] + fe[idx] + cb[idx];
            __builtin_nontemporal_store(v, &dst[idx]);
        }
    } else {
#pragma unroll
        for (int j = 0; j < 4; ++j) {
            int idx = lane + 64 * j;
            f32x4 v = te[idx] + pe[idx] + fe[idx];
            __builtin_nontemporal_store(v, &dst[idx]);
        }
    }

    if (lane == 0)
        out_mask[bs] = (et == 0) ? 1.0f : 0.0f;
}

// ---------------------------------------------------------------------------
extern "C" void kernel_launch(void* const* d_in, const int* in_sizes, int n_in,
                              void* d_out, int out_size, void* d_ws, size_t ws_size,
                              hipStream_t stream) {
    const int*   element_types   = (const int*)  d_in[0];
    const int*   element_indices = (const int*)  d_in[1];
    const float* style_vectors   = (const float*)d_in[2];
    const float* page_captions   = (const float*)d_in[3];
    const float* type_emb        = (const float*)d_in[4];
    const float* pos_emb         = (const float*)d_in[5];
    const float* style_w1        = (const float*)d_in[6];
    const float* style_b1        = (const float*)d_in[7];
    const float* style_w2        = (const float*)d_in[8];
    const float* style_b2        = (const float*)d_in[9];
    const float* text_w          = (const float*)d_in[10];
    const float* text_b          = (const float*)d_in[11];
    const float* final_pos_emb   = (const float*)d_in[12];

    float* part = (float*)d_ws;                           // 4*256*1024 = 4 MB
    float* comb = (float*)d_ws + 4 * BATCH * D;           // 256*1024   = 1 MB

    float* out_emb  = (float*)d_out;                      // 256*128*1024
    float* out_mask = (float*)d_out + BATCH * SEQ * D;    // 256*128

    // 1) split-K GEMM, 512 blocks (2 blocks/CU)
    gemm_fused<<<dim3(BATCH / 32, D / 64, 4), 256, 0, stream>>>(
        style_vectors, page_captions, style_w1, style_b1,
        style_w2, style_b2, text_w, text_b, part);

    // 2) combine partials
    reduce_part<<<BATCH * D / 4 / 256, 256, 0, stream>>>(part, comb);

    // 3) big masked gather-add write (4 rows/block, wave-per-row)
    scatter_kernel<<<BATCH * SEQ / 4, 256, 0, stream>>>(
        element_types, element_indices, type_emb, pos_emb, final_pos_emb,
        comb, out_emb, out_mask);
}